// Round 9
// baseline (33.999 us; speedup 1.0000x reference)
//
#include <hip/hip_runtime.h>
#include <cmath>

#ifndef M_PI
#define M_PI 3.14159265358979323846
#endif

typedef _Float16 h2 __attribute__((ext_vector_type(2)));

namespace {

constexpr int VDIM = 512;
constexpr int RDIM = 1024;
constexpr int NRP = VDIM / 2;      // 256 row-pairs

constexpr int PAIR_W = 28;         // h2 per sorted-26 pair row (112 B)
constexpr int GAP_W = 8;           // h2 per sorted gap-8 row (32 B)
constexpr size_t PAIRS_H2 = (size_t)NRP * RDIM * PAIR_W;  // h2 elements
constexpr size_t GAPS_H2 = (size_t)NRP * RDIM * GAP_W;

struct Net {
  int cnt;
  int a[96];
  int b[96];
};

// Batcher odd-even mergesort (arbitrary n), descending (max to low index).
constexpr Net make_batcher(int n) {
  Net net{};
  net.cnt = 0;
  for (int p = 1; p < n; p *= 2)
    for (int k = p; k >= 1; k /= 2)
      for (int j = k % p; j + k < n; j += 2 * k)
        for (int i = 0; i < k && i + j + k < n; ++i)
          if ((i + j) / (2 * p) == (i + j + k) / (2 * p)) {
            net.a[net.cnt] = i + j;
            net.b[net.cnt] = i + j + k;
            ++net.cnt;
          }
  return net;
}

// Descending sorter for a BITONIC input of length n (front +inf pads elided).
constexpr Net make_bitonic_desc(int n) {
  int P = 1;
  while (P < n) P *= 2;
  int F = P - n;
  Net net{};
  net.cnt = 0;
  for (int d = P / 2; d >= 1; d /= 2)
    for (int i = F; i + d < P; ++i)
      if ((i & d) == 0) {
        net.a[net.cnt] = i - F;
        net.b[net.cnt] = i - F + d;
        ++net.cnt;
      }
  return net;
}

constexpr Net NET8 = make_batcher(8);
constexpr Net NET5 = make_batcher(5);
constexpr Net B13 = make_bitonic_desc(13);
constexpr Net B16 = make_bitonic_desc(16);
constexpr Net B26 = make_bitonic_desc(26);
constexpr Net B32 = make_bitonic_desc(32);
constexpr Net B36 = make_bitonic_desc(36);

}  // namespace

__device__ __forceinline__ h2 mk2(_Float16 a, _Float16 b) {
  h2 v;
  v.x = a;
  v.y = b;
  return v;
}
__device__ __forceinline__ h2 pmax(h2 a, h2 b) { return __builtin_elementwise_max(a, b); }
__device__ __forceinline__ h2 pmin(h2 a, h2 b) { return __builtin_elementwise_min(a, b); }
__device__ __forceinline__ h2 bch(float f) { return __builtin_bit_cast(h2, f); }
__device__ __forceinline__ float bcf(h2 h) { return __builtin_bit_cast(float, h); }

#define DEF_NET(NAME, NET, L)                                       \
  __device__ __forceinline__ void NAME(h2(&v)[L]) {                 \
    _Pragma("unroll") for (int c = 0; c < NET.cnt; ++c) {           \
      h2 a = v[NET.a[c]], b = v[NET.b[c]];                          \
      v[NET.a[c]] = pmax(a, b);                                     \
      v[NET.b[c]] = pmin(a, b);                                     \
    }                                                               \
  }

DEF_NET(net8p, NET8, 8)
DEF_NET(net5p, NET5, 5)
DEF_NET(b13p, B13, 13)
DEF_NET(b16p, B16, 16)
DEF_NET(b26p, B26, 26)
DEF_NET(b32p, B32, 32)
DEF_NET(b36p, B36, 36)

// one column, both rows packed: f = sorted-13 desc, g = sorted gap-8 desc
__device__ __forceinline__ void col_chain(const h2 (&c)[13], h2 (&f)[13], h2 (&g)[8]) {
  g[0] = c[0]; g[1] = c[1]; g[2] = c[2]; g[3] = c[3];
  g[4] = c[9]; g[5] = c[10]; g[6] = c[11]; g[7] = c[12];
  net8p(g);
  h2 m[5] = {c[4], c[5], c[6], c[7], c[8]};
  net5p(m);
#pragma unroll
  for (int p = 0; p < 8; ++p) f[p] = g[p];
  f[8] = m[4]; f[9] = m[3]; f[10] = m[2]; f[11] = m[1]; f[12] = m[0];
  b13p(f);
}

__device__ __forceinline__ void ld26(const h2* __restrict__ row, h2 (&d)[26]) {
#pragma unroll
  for (int k = 0; k < 6; ++k) {
    float4 w = *(const float4*)(row + 4 * k);
    d[4 * k + 0] = bch(w.x); d[4 * k + 1] = bch(w.y);
    d[4 * k + 2] = bch(w.z); d[4 * k + 3] = bch(w.w);
  }
  float2 w = *(const float2*)(row + 24);
  d[24] = bch(w.x); d[25] = bch(w.y);
}

__device__ __forceinline__ void ld8g(const h2* __restrict__ row, h2 (&d)[8]) {
  float4 a = *(const float4*)(row);
  float4 b = *(const float4*)(row + 4);
  d[0] = bch(a.x); d[1] = bch(a.y); d[2] = bch(a.z); d[3] = bch(a.w);
  d[4] = bch(b.x); d[5] = bch(b.y); d[6] = bch(b.z); d[7] = bch(b.w);
}

// top-36 multiset of two descending sorted-26 lists -> bitonic-36
__device__ __forceinline__ void cap36(h2 (&S)[36], const h2 (&x)[26], const h2 (&y)[26]) {
#pragma unroll
  for (int i = 0; i < 10; ++i) S[i] = x[i];
#pragma unroll
  for (int i = 10; i < 26; ++i) S[i] = pmax(x[i], y[35 - i]);
#pragma unroll
  for (int i = 26; i < 36; ++i) S[i] = y[35 - i];
}

// ---- K1: per-(row-pair, column-pair) sort, results to workspace ----
__global__ __launch_bounds__(256, 4) void k1_stage(const float* __restrict__ in,
                                                   h2* __restrict__ pairs,
                                                   h2* __restrict__ gaps) {
  const int c = blockIdx.x * 256 + threadIdx.x;  // 0..1023 (left column of pair)
  const int rp = blockIdx.y;                     // 0..255
  const int r0 = rp * 2;
  const int cn = (c + 1) & (RDIM - 1);

  float ax[14], ay[14];
#pragma unroll
  for (int dy = 0; dy < 14; ++dy) {
    const int rb = ((r0 + dy - 6) & (VDIM - 1)) << 10;
    ax[dy] = in[rb + c];
    ay[dy] = in[rb + cn];
  }
  h2 cL[13], cR[13];
#pragma unroll
  for (int dy = 0; dy < 13; ++dy) {
    cL[dy] = mk2((_Float16)ax[dy], (_Float16)ax[dy + 1]);
    cR[dy] = mk2((_Float16)ay[dy], (_Float16)ay[dy + 1]);
  }
  h2 fL[13], gL[8], fR[13], gR[8];
  col_chain(cL, fL, gL);
  col_chain(cR, fR, gR);
  h2 v[26];
#pragma unroll
  for (int j = 0; j < 13; ++j) v[j] = fL[j];
#pragma unroll
  for (int j = 0; j < 13; ++j) v[13 + j] = fR[12 - j];
  b26p(v);  // sorted-26 desc, both rows

  h2* prow = pairs + (size_t)(rp * RDIM + c) * PAIR_W;
#pragma unroll
  for (int k = 0; k < 6; ++k)
    *(float4*)(prow + 4 * k) = make_float4(bcf(v[4 * k]), bcf(v[4 * k + 1]),
                                           bcf(v[4 * k + 2]), bcf(v[4 * k + 3]));
  *(float2*)(prow + 24) = make_float2(bcf(v[24]), bcf(v[25]));

  h2* grow = gaps + (size_t)(rp * RDIM + c) * GAP_W;
  *(float4*)(grow) = make_float4(bcf(gL[0]), bcf(gL[1]), bcf(gL[2]), bcf(gL[3]));
  *(float4*)(grow + 4) = make_float4(bcf(gL[4]), bcf(gL[5]), bcf(gL[6]), bcf(gL[7]));
}

// ---- K2: per-pixel-pair selection from workspace ----
__global__ __launch_bounds__(256, 4) void k2_select(const h2* __restrict__ pairs,
                                                    const h2* __restrict__ gaps,
                                                    float* __restrict__ out, float alpha) {
  const int c = blockIdx.x * 256 + threadIdx.x;  // pixel column
  const int rp = blockIdx.y;
  const int r0 = rp * 2;
  const h2* prow = pairs + (size_t)rp * RDIM * PAIR_W;
  const h2* grow = gaps + (size_t)rp * RDIM * GAP_W;

  auto P = [&](int d) { return prow + (size_t)((c + d + RDIM) & (RDIM - 1)) * PAIR_W; };
  auto G = [&](int d) { return grow + (size_t)((c + d + RDIM) & (RDIM - 1)) * GAP_W; };

  h2 S[36];
  {  // B-side full cols (dx +3..+6) as pairs (c+3,c+4) and (c+5,c+6)
    h2 x[26], y[26];
    ld26(P(3), x);
    ld26(P(5), y);
    cap36(S, x, y);
  }
  // issue gap loads before the sort chain
  h2 gc0[8], gc1[8], gc2[8], gc3[8];
  ld8g(G(-2), gc0);
  ld8g(G(-1), gc1);
  ld8g(G(0), gc2);
  ld8g(G(1), gc3);
  b36p(S);  // #1

  {  // gap merge tree: 4 cols -> sorted-32, fold into S
    h2 g1[16], g2[16];
#pragma unroll
    for (int j = 0; j < 8; ++j) { g1[j] = gc0[j]; g1[8 + j] = gc1[7 - j]; }
    b16p(g1);
#pragma unroll
    for (int j = 0; j < 8; ++j) { g2[j] = gc2[j]; g2[8 + j] = gc3[7 - j]; }
    b16p(g2);
    h2 Gm[32];
#pragma unroll
    for (int j = 0; j < 16; ++j) { Gm[j] = g1[j]; Gm[16 + j] = g2[15 - j]; }
    b32p(Gm);
#pragma unroll
    for (int i = 4; i < 36; ++i) S[i] = pmax(S[i], Gm[35 - i]);
  }
  h2 gc4[8];
  ld8g(G(2), gc4);
  b36p(S);  // #2

#pragma unroll
  for (int i = 28; i < 36; ++i) S[i] = pmax(S[i], gc4[35 - i]);
  h2 x1[26];
  ld26(P(-6), x1);  // A-pair 1 (dx -6,-5)
  b36p(S);  // #3

#pragma unroll
  for (int i = 10; i < 36; ++i) S[i] = pmax(S[i], x1[35 - i]);
  h2 q[26];
  ld26(P(-4), q);  // A-pair 2 (dx -4,-3)
  b36p(S);  // #4

  // final rank identity: ans = min(S_9, min_{i=10..35} max(S_i, q_{35-i}))
  h2 r = S[9];
#pragma unroll
  for (int i = 10; i < 36; ++i) r = pmin(r, pmax(S[i], q[35 - i]));

  out[(r0 << 10) + c] = alpha * (float)r.x;
  out[((r0 + 1) << 10) + c] = alpha * (float)r.y;
}

// ---- host-side faithful port of the reference ALPHA computation ----
static double log_factorial_port(int n_) {
  double n = n_ + 1.0;
  if (n < 9.0) {
    double f = 1.0;
    for (int i = 2; i <= (int)(n + 0.5); ++i) f *= (double)i;
    return log(f);
  }
  return 0.5 * (log(2.0 * M_PI) - log(n)) +
         n * (log(n + 1.0 / (12.0 * n - 1.0 / (10.0 * n))) - 1.0);
}

static double cfar_fun(int k, int n, double t, double pfa) {
  double s = 0.0;
  for (int i = n; i > n - k; --i) s += log((double)i + t);
  return log_factorial_port(n) - log_factorial_port(n - k) - s - log(pfa);
}

static float compute_alpha() {
  double lo = 1.0, hi = 1e32;
  for (int it = 0; it < 300; ++it) {
    double mid = 0.5 * (lo + hi);
    if (cfar_fun(108, 144, mid, 1e-5) > 0.0)
      lo = mid;
    else
      hi = mid;
  }
  return (float)(0.5 * (lo + hi));
}

static const float g_alpha = compute_alpha();

extern "C" void kernel_launch(void* const* d_in, const int* in_sizes, int n_in,
                              void* d_out, int out_size, void* d_ws, size_t ws_size,
                              hipStream_t stream) {
  const float* in = (const float*)d_in[0];
  float* out = (float*)d_out;
  h2* pairs = (h2*)d_ws;
  h2* gaps = pairs + PAIRS_H2;

  dim3 block(256, 1);
  dim3 grid(RDIM / 256, NRP);
  hipLaunchKernelGGL(k1_stage, grid, block, 0, stream, in, pairs, gaps);
  hipLaunchKernelGGL(k2_select, grid, block, 0, stream, pairs, gaps, out, g_alpha);
}

// Round 10
// 21.033 us; speedup vs baseline: 1.6165x; 1.6165x over previous
//
#include <hip/hip_runtime.h>
#include <cmath>

#ifndef M_PI
#define M_PI 3.14159265358979323846
#endif

typedef _Float16 h2 __attribute__((ext_vector_type(2)));

namespace {

constexpr int VDIM = 512;
constexpr int RDIM = 1024;
constexpr int TX = 256;          // pixel columns per block
constexpr int COLS = TX + 12;    // 268 cols incl. halo
constexpr int NPAIR = COLS - 1;  // 267 adjacent-col pairs

struct Net {
  int cnt;
  int a[96];
  int b[96];
};

// Batcher odd-even mergesort (arbitrary n), descending (max to low index).
constexpr Net make_batcher(int n) {
  Net net{};
  net.cnt = 0;
  for (int p = 1; p < n; p *= 2)
    for (int k = p; k >= 1; k /= 2)
      for (int j = k % p; j + k < n; j += 2 * k)
        for (int i = 0; i < k && i + j + k < n; ++i)
          if ((i + j) / (2 * p) == (i + j + k) / (2 * p)) {
            net.a[net.cnt] = i + j;
            net.b[net.cnt] = i + j + k;
            ++net.cnt;
          }
  return net;
}

// Descending sorter for a BITONIC input of length n (front +inf pads elided).
constexpr Net make_bitonic_desc(int n) {
  int P = 1;
  while (P < n) P *= 2;
  int F = P - n;
  Net net{};
  net.cnt = 0;
  for (int d = P / 2; d >= 1; d /= 2)
    for (int i = F; i + d < P; ++i)
      if ((i & d) == 0) {
        net.a[net.cnt] = i - F;
        net.b[net.cnt] = i - F + d;
        ++net.cnt;
      }
  return net;
}

constexpr Net NET8 = make_batcher(8);
constexpr Net NET5 = make_batcher(5);
constexpr Net B13 = make_bitonic_desc(13);
constexpr Net B16 = make_bitonic_desc(16);
constexpr Net B26 = make_bitonic_desc(26);
constexpr Net B32 = make_bitonic_desc(32);
constexpr Net B36 = make_bitonic_desc(36);

}  // namespace

__device__ __forceinline__ h2 mk2(_Float16 a, _Float16 b) {
  h2 v;
  v.x = a;
  v.y = b;
  return v;
}
__device__ __forceinline__ h2 pmax(h2 a, h2 b) { return __builtin_elementwise_max(a, b); }
__device__ __forceinline__ h2 pmin(h2 a, h2 b) { return __builtin_elementwise_min(a, b); }
__device__ __forceinline__ h2 bch(float f) { return __builtin_bit_cast(h2, f); }
__device__ __forceinline__ float bcf(h2 h) { return __builtin_bit_cast(float, h); }

#define DEF_NET(NAME, NET, L)                                       \
  __device__ __forceinline__ void NAME(h2(&v)[L]) {                 \
    _Pragma("unroll") for (int c = 0; c < NET.cnt; ++c) {           \
      h2 a = v[NET.a[c]], b = v[NET.b[c]];                          \
      v[NET.a[c]] = pmax(a, b);                                     \
      v[NET.b[c]] = pmin(a, b);                                     \
    }                                                               \
  }

DEF_NET(net8p, NET8, 8)
DEF_NET(net5p, NET5, 5)
DEF_NET(b13p, B13, 13)
DEF_NET(b16p, B16, 16)
DEF_NET(b26p, B26, 26)
DEF_NET(b32p, B32, 32)
DEF_NET(b36p, B36, 36)

// one column, both rows packed: f = sorted-13 desc, g = sorted gap-8 desc
__device__ __forceinline__ void col_chain(const h2 (&c)[13], h2 (&f)[13], h2 (&g)[8]) {
  g[0] = c[0]; g[1] = c[1]; g[2] = c[2]; g[3] = c[3];
  g[4] = c[9]; g[5] = c[10]; g[6] = c[11]; g[7] = c[12];
  net8p(g);
  h2 m[5] = {c[4], c[5], c[6], c[7], c[8]};
  net5p(m);
#pragma unroll
  for (int p = 0; p < 8; ++p) f[p] = g[p];
  f[8] = m[4]; f[9] = m[3]; f[10] = m[2]; f[11] = m[1]; f[12] = m[0];
  b13p(f);
}

// chunked pair storage: SPc[j][row], 16B row stride -> lane-contiguous b128
__device__ __forceinline__ void ld26(const float4 (&SPc)[7][NPAIR], int r, h2 (&d)[26]) {
#pragma unroll
  for (int k = 0; k < 6; ++k) {
    float4 w = SPc[k][r];
    d[4 * k + 0] = bch(w.x); d[4 * k + 1] = bch(w.y);
    d[4 * k + 2] = bch(w.z); d[4 * k + 3] = bch(w.w);
  }
  float4 w = SPc[6][r];
  d[24] = bch(w.x); d[25] = bch(w.y);
}

// gap-8 col from the split 16B-row arrays (lane-contiguous)
__device__ __forceinline__ void ldg8(const h2* SGa, const h2* SGb, int c, h2 (&d)[8]) {
  float4 a = *(const float4*)(SGa + 4 * c);
  float4 b = *(const float4*)(SGb + 4 * c);
  d[0] = bch(a.x); d[1] = bch(a.y); d[2] = bch(a.z); d[3] = bch(a.w);
  d[4] = bch(b.x); d[5] = bch(b.y); d[6] = bch(b.z); d[7] = bch(b.w);
}

// top-36 multiset of two descending sorted-26 lists -> bitonic-36
__device__ __forceinline__ void cap36(h2 (&S)[36], const h2 (&x)[26], const h2 (&y)[26]) {
#pragma unroll
  for (int i = 0; i < 10; ++i) S[i] = x[i];
#pragma unroll
  for (int i = 10; i < 26; ++i) S[i] = pmax(x[i], y[35 - i]);
#pragma unroll
  for (int i = 26; i < 36; ++i) S[i] = y[35 - i];
}

__global__ __launch_bounds__(256, 4) void cfar_os_kernel(const float* __restrict__ in,
                                                         float* __restrict__ out,
                                                         float alpha) {
  __shared__ __attribute__((aligned(16))) float4 SPc[7][NPAIR];  // sorted-26 pairs, chunked
  __shared__ __attribute__((aligned(16))) h2 SGa[COLS * 4];      // gap-8 lo half
  __shared__ __attribute__((aligned(16))) h2 SGb[COLS * 4];      // gap-8 hi half

  const int t = threadIdx.x;
  const int r0 = blockIdx.y * 2;  // row pair (r0 in .x, r0+1 in .y)
  const int c0 = blockIdx.x * TX;

  // ---- cooperative stage: col-pair task, 2 cols x 2 rows per task ----
  for (int cc = t; cc < NPAIR; cc += 256) {
    const int gl = (c0 + cc - 6) & (RDIM - 1);
    const int gr = (gl + 1) & (RDIM - 1);
    float rwx[14], rwy[14];
#pragma unroll
    for (int dy = 0; dy < 14; ++dy) {
      const int rb = ((r0 + dy - 6) & (VDIM - 1)) << 10;
      rwx[dy] = in[rb + gl];
      rwy[dy] = in[rb + gr];
    }
    h2 cL[13], cR[13];
#pragma unroll
    for (int dy = 0; dy < 13; ++dy) {
      cL[dy] = mk2((_Float16)rwx[dy], (_Float16)rwx[dy + 1]);
      cR[dy] = mk2((_Float16)rwy[dy], (_Float16)rwy[dy + 1]);
    }
    h2 fL[13], gL[8], fR[13], gR[8];
    col_chain(cL, fL, gL);
    col_chain(cR, fR, gR);
    h2 v[26];
#pragma unroll
    for (int j = 0; j < 13; ++j) v[j] = fL[j];
#pragma unroll
    for (int j = 0; j < 13; ++j) v[13 + j] = fR[12 - j];
    b26p(v);  // sorted-26 desc, both rows

#pragma unroll
    for (int k = 0; k < 6; ++k)
      SPc[k][cc] = make_float4(bcf(v[4 * k]), bcf(v[4 * k + 1]),
                               bcf(v[4 * k + 2]), bcf(v[4 * k + 3]));
    {
      float ninf = bcf(mk2((_Float16)(-INFINITY), (_Float16)(-INFINITY)));
      SPc[6][cc] = make_float4(bcf(v[24]), bcf(v[25]), ninf, ninf);
    }

    *(float4*)(SGa + 4 * cc) = make_float4(bcf(gL[0]), bcf(gL[1]), bcf(gL[2]), bcf(gL[3]));
    *(float4*)(SGb + 4 * cc) = make_float4(bcf(gL[4]), bcf(gL[5]), bcf(gL[6]), bcf(gL[7]));
  }
  __syncthreads();

  // ---- per-pixel-pair phase: single running sorted top-36 accumulator ----
  h2 S[36];
  {  // B-side full cols (dx +3..+6) as pairs (t+9) and (t+11)
    h2 x[26], y[26];
    ld26(SPc, t + 9, x);
    ld26(SPc, t + 11, y);
    cap36(S, x, y);
  }
  // issue gap loads before the sort chain
  h2 gc0[8], gc1[8], gc2[8], gc3[8];
  ldg8(SGa, SGb, t + 4, gc0);
  ldg8(SGa, SGb, t + 5, gc1);
  ldg8(SGa, SGb, t + 6, gc2);
  ldg8(SGa, SGb, t + 7, gc3);
  b36p(S);  // #1

  {  // gap merge tree: 4 cols -> sorted-32, fold into S
    h2 g1[16], g2[16];
#pragma unroll
    for (int j = 0; j < 8; ++j) { g1[j] = gc0[j]; g1[8 + j] = gc1[7 - j]; }
    b16p(g1);
#pragma unroll
    for (int j = 0; j < 8; ++j) { g2[j] = gc2[j]; g2[8 + j] = gc3[7 - j]; }
    b16p(g2);
    h2 Gm[32];
#pragma unroll
    for (int j = 0; j < 16; ++j) { Gm[j] = g1[j]; Gm[16 + j] = g2[15 - j]; }
    b32p(Gm);
#pragma unroll
    for (int i = 4; i < 36; ++i) S[i] = pmax(S[i], Gm[35 - i]);
  }
  h2 gc4[8];
  ldg8(SGa, SGb, t + 8, gc4);
  b36p(S);  // #2

#pragma unroll
  for (int i = 28; i < 36; ++i) S[i] = pmax(S[i], gc4[35 - i]);
  h2 x1[26];
  ld26(SPc, t + 0, x1);  // A-pair 1 (dx -6,-5)
  b36p(S);  // #3

#pragma unroll
  for (int i = 10; i < 36; ++i) S[i] = pmax(S[i], x1[35 - i]);
  h2 q[26];
  ld26(SPc, t + 2, q);  // A-pair 2 (dx -4,-3)
  b36p(S);  // #4

  // final rank identity: ans = min(S_9, min_{i=10..35} max(S_i, q_{35-i}))
  h2 r = S[9];
#pragma unroll
  for (int i = 10; i < 36; ++i) r = pmin(r, pmax(S[i], q[35 - i]));

  const int oc = c0 + t;
  out[(r0 << 10) + oc] = alpha * (float)r.x;
  out[((r0 + 1) << 10) + oc] = alpha * (float)r.y;
}

// ---- host-side faithful port of the reference ALPHA computation ----
static double log_factorial_port(int n_) {
  double n = n_ + 1.0;
  if (n < 9.0) {
    double f = 1.0;
    for (int i = 2; i <= (int)(n + 0.5); ++i) f *= (double)i;
    return log(f);
  }
  return 0.5 * (log(2.0 * M_PI) - log(n)) +
         n * (log(n + 1.0 / (12.0 * n - 1.0 / (10.0 * n))) - 1.0);
}

static double cfar_fun(int k, int n, double t, double pfa) {
  double s = 0.0;
  for (int i = n; i > n - k; --i) s += log((double)i + t);
  return log_factorial_port(n) - log_factorial_port(n - k) - s - log(pfa);
}

static float compute_alpha() {
  double lo = 1.0, hi = 1e32;
  for (int it = 0; it < 300; ++it) {
    double mid = 0.5 * (lo + hi);
    if (cfar_fun(108, 144, mid, 1e-5) > 0.0)
      lo = mid;
    else
      hi = mid;
  }
  return (float)(0.5 * (lo + hi));
}

static const float g_alpha = compute_alpha();

extern "C" void kernel_launch(void* const* d_in, const int* in_sizes, int n_in,
                              void* d_out, int out_size, void* d_ws, size_t ws_size,
                              hipStream_t stream) {
  const float* in = (const float*)d_in[0];
  float* out = (float*)d_out;
  dim3 block(TX, 1);
  dim3 grid(RDIM / TX, VDIM / 2);
  hipLaunchKernelGGL(cfar_os_kernel, grid, block, 0, stream, in, out, g_alpha);
}

// Round 11
// 19.827 us; speedup vs baseline: 1.7148x; 1.0609x over previous
//
#include <hip/hip_runtime.h>
#include <cmath>

#ifndef M_PI
#define M_PI 3.14159265358979323846
#endif

typedef _Float16 h2 __attribute__((ext_vector_type(2)));

namespace {

constexpr int VDIM = 512;
constexpr int RDIM = 1024;
constexpr int TX = 256;          // pixel columns per block
constexpr int COLS = TX + 12;    // 268 cols incl. halo
constexpr int NPAIR = COLS - 1;  // 267 adjacent-col pairs

constexpr int SP_W = 28;  // h2 per pair row (112 B, 16B-aligned)
constexpr int SG_W = 8;   // h2 per gap row

struct Net {
  int cnt;
  int a[96];
  int b[96];
};

// Batcher odd-even mergesort (arbitrary n), descending (max to low index).
constexpr Net make_batcher(int n) {
  Net net{};
  net.cnt = 0;
  for (int p = 1; p < n; p *= 2)
    for (int k = p; k >= 1; k /= 2)
      for (int j = k % p; j + k < n; j += 2 * k)
        for (int i = 0; i < k && i + j + k < n; ++i)
          if ((i + j) / (2 * p) == (i + j + k) / (2 * p)) {
            net.a[net.cnt] = i + j;
            net.b[net.cnt] = i + j + k;
            ++net.cnt;
          }
  return net;
}

// Descending sorter for a BITONIC input of length n (front +inf pads elided).
constexpr Net make_bitonic_desc(int n) {
  int P = 1;
  while (P < n) P *= 2;
  int F = P - n;
  Net net{};
  net.cnt = 0;
  for (int d = P / 2; d >= 1; d /= 2)
    for (int i = F; i + d < P; ++i)
      if ((i & d) == 0) {
        net.a[net.cnt] = i - F;
        net.b[net.cnt] = i - F + d;
        ++net.cnt;
      }
  return net;
}

constexpr Net NET8 = make_batcher(8);
constexpr Net NET5 = make_batcher(5);
constexpr Net B13 = make_bitonic_desc(13);
constexpr Net B16 = make_bitonic_desc(16);
constexpr Net B26 = make_bitonic_desc(26);
constexpr Net B32 = make_bitonic_desc(32);
constexpr Net B36 = make_bitonic_desc(36);

}  // namespace

__device__ __forceinline__ h2 mk2(_Float16 a, _Float16 b) {
  h2 v;
  v.x = a;
  v.y = b;
  return v;
}
__device__ __forceinline__ h2 pmax(h2 a, h2 b) { return __builtin_elementwise_max(a, b); }
__device__ __forceinline__ h2 pmin(h2 a, h2 b) { return __builtin_elementwise_min(a, b); }
__device__ __forceinline__ h2 bch(float f) { return __builtin_bit_cast(h2, f); }
__device__ __forceinline__ float bcf(h2 h) { return __builtin_bit_cast(float, h); }

#define DEF_NET(NAME, NET, L)                                       \
  __device__ __forceinline__ void NAME(h2(&v)[L]) {                 \
    _Pragma("unroll") for (int c = 0; c < NET.cnt; ++c) {           \
      h2 a = v[NET.a[c]], b = v[NET.b[c]];                          \
      v[NET.a[c]] = pmax(a, b);                                     \
      v[NET.b[c]] = pmin(a, b);                                     \
    }                                                               \
  }

DEF_NET(net8p, NET8, 8)
DEF_NET(net5p, NET5, 5)
DEF_NET(b13p, B13, 13)
DEF_NET(b16p, B16, 16)
DEF_NET(b26p, B26, 26)
DEF_NET(b32p, B32, 32)
DEF_NET(b36p, B36, 36)

// one column, both rows packed: f = sorted-13 desc, g = sorted gap-8 desc
__device__ __forceinline__ void col_chain(const h2 (&c)[13], h2 (&f)[13], h2 (&g)[8]) {
  g[0] = c[0]; g[1] = c[1]; g[2] = c[2]; g[3] = c[3];
  g[4] = c[9]; g[5] = c[10]; g[6] = c[11]; g[7] = c[12];
  net8p(g);
  h2 m[5] = {c[4], c[5], c[6], c[7], c[8]};
  net5p(m);
#pragma unroll
  for (int p = 0; p < 8; ++p) f[p] = g[p];
  f[8] = m[4]; f[9] = m[3]; f[10] = m[2]; f[11] = m[1]; f[12] = m[0];
  b13p(f);
}

// flat pair rows (112B stride): 7x ds_read_b128 off one base + imm offsets
__device__ __forceinline__ void ld26(const h2* __restrict__ row, h2 (&d)[26]) {
#pragma unroll
  for (int k = 0; k < 6; ++k) {
    float4 w = *(const float4*)(row + 4 * k);
    d[4 * k + 0] = bch(w.x); d[4 * k + 1] = bch(w.y);
    d[4 * k + 2] = bch(w.z); d[4 * k + 3] = bch(w.w);
  }
  float2 w = *(const float2*)(row + 24);
  d[24] = bch(w.x); d[25] = bch(w.y);
}

__device__ __forceinline__ void ldg8(const h2* SGa, const h2* SGb, int c, h2 (&d)[8]) {
  float4 a = *(const float4*)(SGa + 4 * c);
  float4 b = *(const float4*)(SGb + 4 * c);
  d[0] = bch(a.x); d[1] = bch(a.y); d[2] = bch(a.z); d[3] = bch(a.w);
  d[4] = bch(b.x); d[5] = bch(b.y); d[6] = bch(b.z); d[7] = bch(b.w);
}

// top-36 multiset of two descending sorted-26 lists -> bitonic-36
__device__ __forceinline__ void cap36(h2 (&S)[36], const h2 (&x)[26], const h2 (&y)[26]) {
#pragma unroll
  for (int i = 0; i < 10; ++i) S[i] = x[i];
#pragma unroll
  for (int i = 10; i < 26; ++i) S[i] = pmax(x[i], y[35 - i]);
#pragma unroll
  for (int i = 26; i < 36; ++i) S[i] = y[35 - i];
}

__global__ __launch_bounds__(256, 4) void cfar_os_kernel(const float* __restrict__ in,
                                                         float* __restrict__ out,
                                                         float alpha) {
  __shared__ __attribute__((aligned(16))) h2 SP[NPAIR * SP_W];  // sorted-26 pairs, flat
  __shared__ __attribute__((aligned(16))) h2 SGa[COLS * 4];     // gap-8 lo half
  __shared__ __attribute__((aligned(16))) h2 SGb[COLS * 4];     // gap-8 hi half

  const int t = threadIdx.x;
  const int r0 = blockIdx.y * 2;  // row pair (r0 in .x, r0+1 in .y)
  const int c0 = blockIdx.x * TX;

  // ---- cooperative stage: col-pair task, 2 cols x 2 rows per task ----
  for (int cc = t; cc < NPAIR; cc += 256) {
    const int gl = (c0 + cc - 6) & (RDIM - 1);
    const int gr = (gl + 1) & (RDIM - 1);
    float rwx[14], rwy[14];
#pragma unroll
    for (int dy = 0; dy < 14; ++dy) {
      const int rb = ((r0 + dy - 6) & (VDIM - 1)) << 10;
      rwx[dy] = in[rb + gl];
      rwy[dy] = in[rb + gr];
    }
    h2 cL[13], cR[13];
#pragma unroll
    for (int dy = 0; dy < 13; ++dy) {
      cL[dy] = mk2((_Float16)rwx[dy], (_Float16)rwx[dy + 1]);
      cR[dy] = mk2((_Float16)rwy[dy], (_Float16)rwy[dy + 1]);
    }
    h2 fL[13], gL[8], fR[13], gR[8];
    col_chain(cL, fL, gL);
    col_chain(cR, fR, gR);
    h2 v[26];
#pragma unroll
    for (int j = 0; j < 13; ++j) v[j] = fL[j];
#pragma unroll
    for (int j = 0; j < 13; ++j) v[13 + j] = fR[12 - j];
    b26p(v);  // sorted-26 desc, both rows

    h2* row = SP + cc * SP_W;
#pragma unroll
    for (int k = 0; k < 6; ++k)
      *(float4*)(row + 4 * k) = make_float4(bcf(v[4 * k]), bcf(v[4 * k + 1]),
                                            bcf(v[4 * k + 2]), bcf(v[4 * k + 3]));
    *(float2*)(row + 24) = make_float2(bcf(v[24]), bcf(v[25]));

    *(float4*)(SGa + 4 * cc) = make_float4(bcf(gL[0]), bcf(gL[1]), bcf(gL[2]), bcf(gL[3]));
    *(float4*)(SGb + 4 * cc) = make_float4(bcf(gL[4]), bcf(gL[5]), bcf(gL[6]), bcf(gL[7]));
  }
  __syncthreads();

  // ---- per-pixel-pair phase ----
  h2 S[36];
  {  // B-side full cols (dx +3..+6): pairs (t+9),(t+11)
    h2 x[26], y[26];
    ld26(SP + (t + 9) * SP_W, x);
    ld26(SP + (t + 11) * SP_W, y);
    cap36(S, x, y);
  }
  // issue all gap loads before the sort chains
  h2 gc0[8], gc1[8], gc2[8], gc3[8], gc4[8];
  ldg8(SGa, SGb, t + 4, gc0);
  ldg8(SGa, SGb, t + 5, gc1);
  ldg8(SGa, SGb, t + 6, gc2);
  ldg8(SGa, SGb, t + 7, gc3);
  ldg8(SGa, SGb, t + 8, gc4);

  b36p(S);  // S-chain #1  (independent of the gap branch below)

  // ---- gap branch (parallel to b36#1): top-36 of the 40 gap cells ----
  h2 T[36];
  {
    h2 g1[16], g2[16];
#pragma unroll
    for (int j = 0; j < 8; ++j) { g1[j] = gc0[j]; g1[8 + j] = gc1[7 - j]; }
    b16p(g1);
#pragma unroll
    for (int j = 0; j < 8; ++j) { g2[j] = gc2[j]; g2[8 + j] = gc3[7 - j]; }
    b16p(g2);
    h2 Gm[32];
#pragma unroll
    for (int j = 0; j < 16; ++j) { Gm[j] = g1[j]; Gm[16 + j] = g2[15 - j]; }
    b32p(Gm);
    // cap 40 -> bitonic 36: [Gm desc (32) | gc4 asc tail]
#pragma unroll
    for (int j = 0; j < 28; ++j) T[j] = Gm[j];
#pragma unroll
    for (int j = 28; j < 32; ++j) T[j] = pmax(Gm[j], gc4[35 - j]);
#pragma unroll
    for (int j = 32; j < 36; ++j) T[j] = gc4[35 - j];
    b36p(T);  // gap branch sort (runs interleaved with b36#1)
  }

  // fold gap top-36 into S
#pragma unroll
  for (int i = 0; i < 36; ++i) S[i] = pmax(S[i], T[35 - i]);
  h2 x1[26];
  ld26(SP + (t + 0) * SP_W, x1);  // A-pair 1 (dx -6,-5)
  b36p(S);  // S-chain #2

#pragma unroll
  for (int i = 10; i < 36; ++i) S[i] = pmax(S[i], x1[35 - i]);
  h2 q[26];
  ld26(SP + (t + 2) * SP_W, q);  // A-pair 2 (dx -4,-3)
  b36p(S);  // S-chain #3

  // final rank identity, tree-min:
  // ans = min(S_9, min_{i=10..35} max(S_i, q_{35-i}))
  h2 mm[27];
#pragma unroll
  for (int i = 0; i < 26; ++i) mm[i] = pmax(S[10 + i], q[25 - i]);
  mm[26] = S[9];
#pragma unroll
  for (int i = 0; i < 13; ++i) mm[i] = pmin(mm[i], mm[i + 13]);  // 13 (idx 26 kept)
  mm[13] = mm[26];
#pragma unroll
  for (int i = 0; i < 7; ++i) mm[i] = pmin(mm[i], mm[i + 7]);
#pragma unroll
  for (int i = 0; i < 3; ++i) mm[i] = pmin(mm[i], mm[i + 3]);
  mm[0] = pmin(pmin(mm[0], mm[1]), pmin(mm[2], mm[6]));

  const int oc = c0 + t;
  out[(r0 << 10) + oc] = alpha * (float)mm[0].x;
  out[((r0 + 1) << 10) + oc] = alpha * (float)mm[0].y;
}

// ---- host-side faithful port of the reference ALPHA computation ----
static double log_factorial_port(int n_) {
  double n = n_ + 1.0;
  if (n < 9.0) {
    double f = 1.0;
    for (int i = 2; i <= (int)(n + 0.5); ++i) f *= (double)i;
    return log(f);
  }
  return 0.5 * (log(2.0 * M_PI) - log(n)) +
         n * (log(n + 1.0 / (12.0 * n - 1.0 / (10.0 * n))) - 1.0);
}

static double cfar_fun(int k, int n, double t, double pfa) {
  double s = 0.0;
  for (int i = n; i > n - k; --i) s += log((double)i + t);
  return log_factorial_port(n) - log_factorial_port(n - k) - s - log(pfa);
}

static float compute_alpha() {
  double lo = 1.0, hi = 1e32;
  for (int it = 0; it < 300; ++it) {
    double mid = 0.5 * (lo + hi);
    if (cfar_fun(108, 144, mid, 1e-5) > 0.0)
      lo = mid;
    else
      hi = mid;
  }
  return (float)(0.5 * (lo + hi));
}

static const float g_alpha = compute_alpha();

extern "C" void kernel_launch(void* const* d_in, const int* in_sizes, int n_in,
                              void* d_out, int out_size, void* d_ws, size_t ws_size,
                              hipStream_t stream) {
  const float* in = (const float*)d_in[0];
  float* out = (float*)d_out;
  dim3 block(TX, 1);
  dim3 grid(RDIM / TX, VDIM / 2);
  hipLaunchKernelGGL(cfar_os_kernel, grid, block, 0, stream, in, out, g_alpha);
}

// Round 12
// 19.265 us; speedup vs baseline: 1.7648x; 1.0292x over previous
//
#include <hip/hip_runtime.h>
#include <cmath>

#ifndef M_PI
#define M_PI 3.14159265358979323846
#endif

typedef _Float16 h2 __attribute__((ext_vector_type(2)));

namespace {

constexpr int VDIM = 512;
constexpr int RDIM = 1024;
constexpr int TX = 256;          // pixel columns per block
constexpr int COLS = TX + 12;    // 268 cols incl. halo
constexpr int NPAIR = COLS - 1;  // 267 adjacent-col pairs

constexpr int SP_W = 28;  // h2 per pair row (112 B, 16B-aligned)

struct Net {
  int cnt;
  int a[96];
  int b[96];
};

// Batcher odd-even mergesort (arbitrary n), descending (max to low index).
constexpr Net make_batcher(int n) {
  Net net{};
  net.cnt = 0;
  for (int p = 1; p < n; p *= 2)
    for (int k = p; k >= 1; k /= 2)
      for (int j = k % p; j + k < n; j += 2 * k)
        for (int i = 0; i < k && i + j + k < n; ++i)
          if ((i + j) / (2 * p) == (i + j + k) / (2 * p)) {
            net.a[net.cnt] = i + j;
            net.b[net.cnt] = i + j + k;
            ++net.cnt;
          }
  return net;
}

// Descending sorter for a BITONIC input of length n (front +inf pads elided).
constexpr Net make_bitonic_desc(int n) {
  int P = 1;
  while (P < n) P *= 2;
  int F = P - n;
  Net net{};
  net.cnt = 0;
  for (int d = P / 2; d >= 1; d /= 2)
    for (int i = F; i + d < P; ++i)
      if ((i & d) == 0) {
        net.a[net.cnt] = i - F;
        net.b[net.cnt] = i - F + d;
        ++net.cnt;
      }
  return net;
}

constexpr Net NET8 = make_batcher(8);
constexpr Net NET5 = make_batcher(5);
constexpr Net B13 = make_bitonic_desc(13);
constexpr Net B16 = make_bitonic_desc(16);
constexpr Net B26 = make_bitonic_desc(26);
constexpr Net B32 = make_bitonic_desc(32);
constexpr Net B36 = make_bitonic_desc(36);

}  // namespace

__device__ __forceinline__ h2 mk2(_Float16 a, _Float16 b) {
  h2 v;
  v.x = a;
  v.y = b;
  return v;
}
__device__ __forceinline__ h2 pmax(h2 a, h2 b) { return __builtin_elementwise_max(a, b); }
__device__ __forceinline__ h2 pmin(h2 a, h2 b) { return __builtin_elementwise_min(a, b); }
__device__ __forceinline__ h2 bch(float f) { return __builtin_bit_cast(h2, f); }
__device__ __forceinline__ float bcf(h2 h) { return __builtin_bit_cast(float, h); }

#define DEF_NET(NAME, NET, L)                                       \
  __device__ __forceinline__ void NAME(h2(&v)[L]) {                 \
    _Pragma("unroll") for (int c = 0; c < NET.cnt; ++c) {           \
      h2 a = v[NET.a[c]], b = v[NET.b[c]];                          \
      v[NET.a[c]] = pmax(a, b);                                     \
      v[NET.b[c]] = pmin(a, b);                                     \
    }                                                               \
  }

DEF_NET(net8p, NET8, 8)
DEF_NET(net5p, NET5, 5)
DEF_NET(b13p, B13, 13)
DEF_NET(b16p, B16, 16)
DEF_NET(b26p, B26, 26)
DEF_NET(b32p, B32, 32)
DEF_NET(b36p, B36, 36)

// one column, both rows packed: f = sorted-13 desc, g = sorted gap-8 desc
__device__ __forceinline__ void col_chain(const h2 (&c)[13], h2 (&f)[13], h2 (&g)[8]) {
  g[0] = c[0]; g[1] = c[1]; g[2] = c[2]; g[3] = c[3];
  g[4] = c[9]; g[5] = c[10]; g[6] = c[11]; g[7] = c[12];
  net8p(g);
  h2 m[5] = {c[4], c[5], c[6], c[7], c[8]};
  net5p(m);
#pragma unroll
  for (int p = 0; p < 8; ++p) f[p] = g[p];
  f[8] = m[4]; f[9] = m[3]; f[10] = m[2]; f[11] = m[1]; f[12] = m[0];
  b13p(f);
}

// flat pair rows (112B stride): 7x ds_read_b128 off one base + imm offsets
__device__ __forceinline__ void ld26(const h2* __restrict__ row, h2 (&d)[26]) {
#pragma unroll
  for (int k = 0; k < 6; ++k) {
    float4 w = *(const float4*)(row + 4 * k);
    d[4 * k + 0] = bch(w.x); d[4 * k + 1] = bch(w.y);
    d[4 * k + 2] = bch(w.z); d[4 * k + 3] = bch(w.w);
  }
  float2 w = *(const float2*)(row + 24);
  d[24] = bch(w.x); d[25] = bch(w.y);
}

__device__ __forceinline__ void ldg8(const h2* SGa, const h2* SGb, int c, h2 (&d)[8]) {
  float4 a = *(const float4*)(SGa + 4 * c);
  float4 b = *(const float4*)(SGb + 4 * c);
  d[0] = bch(a.x); d[1] = bch(a.y); d[2] = bch(a.z); d[3] = bch(a.w);
  d[4] = bch(b.x); d[5] = bch(b.y); d[6] = bch(b.z); d[7] = bch(b.w);
}

// top-36 multiset of two descending sorted-26 lists -> bitonic-36
__device__ __forceinline__ void cap36(h2 (&S)[36], const h2 (&x)[26], const h2 (&y)[26]) {
#pragma unroll
  for (int i = 0; i < 10; ++i) S[i] = x[i];
#pragma unroll
  for (int i = 10; i < 26; ++i) S[i] = pmax(x[i], y[35 - i]);
#pragma unroll
  for (int i = 26; i < 36; ++i) S[i] = y[35 - i];
}

__global__ __launch_bounds__(256, 4) void cfar_os_kernel(const float* __restrict__ in,
                                                         float* __restrict__ out,
                                                         float alpha) {
  __shared__ __attribute__((aligned(16))) h2 SP[NPAIR * SP_W];  // sorted-26 pairs, flat
  __shared__ __attribute__((aligned(16))) h2 SGa[COLS * 4];     // gap-8 lo half
  __shared__ __attribute__((aligned(16))) h2 SGb[COLS * 4];     // gap-8 hi half

  const int t = threadIdx.x;
  const int r0 = blockIdx.y * 2;  // row pair (r0 in .x, r0+1 in .y)
  const int c0 = blockIdx.x * TX;

  // ---- cooperative stage: col-pair task, 2 cols x 2 rows per task ----
  for (int cc = t; cc < NPAIR; cc += 256) {
    const int gl = (c0 + cc - 6) & (RDIM - 1);
    const int gr = (gl + 1) & (RDIM - 1);
    float rwx[14], rwy[14];
#pragma unroll
    for (int dy = 0; dy < 14; ++dy) {
      const int rb = ((r0 + dy - 6) & (VDIM - 1)) << 10;
      rwx[dy] = in[rb + gl];
      rwy[dy] = in[rb + gr];
    }
    h2 cL[13], cR[13];
#pragma unroll
    for (int dy = 0; dy < 13; ++dy) {
      cL[dy] = mk2((_Float16)rwx[dy], (_Float16)rwx[dy + 1]);
      cR[dy] = mk2((_Float16)rwy[dy], (_Float16)rwy[dy + 1]);
    }
    h2 fL[13], gL[8], fR[13], gR[8];
    col_chain(cL, fL, gL);
    col_chain(cR, fR, gR);
    h2 v[26];
#pragma unroll
    for (int j = 0; j < 13; ++j) v[j] = fL[j];
#pragma unroll
    for (int j = 0; j < 13; ++j) v[13 + j] = fR[12 - j];
    b26p(v);  // sorted-26 desc, both rows

    h2* row = SP + cc * SP_W;
#pragma unroll
    for (int k = 0; k < 6; ++k)
      *(float4*)(row + 4 * k) = make_float4(bcf(v[4 * k]), bcf(v[4 * k + 1]),
                                            bcf(v[4 * k + 2]), bcf(v[4 * k + 3]));
    *(float2*)(row + 24) = make_float2(bcf(v[24]), bcf(v[25]));

    *(float4*)(SGa + 4 * cc) = make_float4(bcf(gL[0]), bcf(gL[1]), bcf(gL[2]), bcf(gL[3]));
    *(float4*)(SGb + 4 * cc) = make_float4(bcf(gL[4]), bcf(gL[5]), bcf(gL[6]), bcf(gL[7]));
  }
  __syncthreads();

  // ---- per-pixel-pair phase: gap branch FIRST (minimal register liveness) ----
  h2 T[36];
  {
    h2 gc0[8], gc1[8], gc2[8], gc3[8], gc4[8];
    ldg8(SGa, SGb, t + 4, gc0);
    ldg8(SGa, SGb, t + 5, gc1);
    ldg8(SGa, SGb, t + 6, gc2);
    ldg8(SGa, SGb, t + 7, gc3);
    ldg8(SGa, SGb, t + 8, gc4);
    h2 g1[16], g2[16];
#pragma unroll
    for (int j = 0; j < 8; ++j) { g1[j] = gc0[j]; g1[8 + j] = gc1[7 - j]; }
    b16p(g1);
#pragma unroll
    for (int j = 0; j < 8; ++j) { g2[j] = gc2[j]; g2[8 + j] = gc3[7 - j]; }
    b16p(g2);
    h2 Gm[32];
#pragma unroll
    for (int j = 0; j < 16; ++j) { Gm[j] = g1[j]; Gm[16 + j] = g2[15 - j]; }
    b32p(Gm);
    // cap 40 -> bitonic 36: [Gm desc (32) | gc4 asc tail]
#pragma unroll
    for (int j = 0; j < 28; ++j) T[j] = Gm[j];
#pragma unroll
    for (int j = 28; j < 32; ++j) T[j] = pmax(Gm[j], gc4[35 - j]);
#pragma unroll
    for (int j = 32; j < 36; ++j) T[j] = gc4[35 - j];
    b36p(T);  // sorted top-36 of the 40 gap cells
  }

  // ---- B-side pairs, fold chain on single accumulator S ----
  h2 S[36];
  {
    h2 x[26], y[26];
    ld26(SP + (t + 9) * SP_W, x);
    ld26(SP + (t + 11) * SP_W, y);
    cap36(S, x, y);
  }
  b36p(S);  // #1

#pragma unroll
  for (int i = 0; i < 36; ++i) S[i] = pmax(S[i], T[35 - i]);  // fold gap top-36
  h2 x1[26];
  ld26(SP + (t + 0) * SP_W, x1);  // A-pair 1 (dx -6,-5)
  b36p(S);  // #2

#pragma unroll
  for (int i = 10; i < 36; ++i) S[i] = pmax(S[i], x1[35 - i]);
  h2 q[26];
  ld26(SP + (t + 2) * SP_W, q);  // A-pair 2 (dx -4,-3)
  b36p(S);  // #3

  // final rank identity, tree-min:
  // ans = min(S_9, min_{i=10..35} max(S_i, q_{35-i}))
  h2 mm[27];
#pragma unroll
  for (int i = 0; i < 26; ++i) mm[i] = pmax(S[10 + i], q[25 - i]);
  mm[26] = S[9];
#pragma unroll
  for (int i = 0; i < 13; ++i) mm[i] = pmin(mm[i], mm[i + 13]);
  mm[13] = mm[26];
#pragma unroll
  for (int i = 0; i < 7; ++i) mm[i] = pmin(mm[i], mm[i + 7]);
#pragma unroll
  for (int i = 0; i < 3; ++i) mm[i] = pmin(mm[i], mm[i + 3]);
  mm[0] = pmin(pmin(mm[0], mm[1]), pmin(mm[2], mm[6]));

  const int oc = c0 + t;
  out[(r0 << 10) + oc] = alpha * (float)mm[0].x;
  out[((r0 + 1) << 10) + oc] = alpha * (float)mm[0].y;
}

// ---- host-side faithful port of the reference ALPHA computation ----
static double log_factorial_port(int n_) {
  double n = n_ + 1.0;
  if (n < 9.0) {
    double f = 1.0;
    for (int i = 2; i <= (int)(n + 0.5); ++i) f *= (double)i;
    return log(f);
  }
  return 0.5 * (log(2.0 * M_PI) - log(n)) +
         n * (log(n + 1.0 / (12.0 * n - 1.0 / (10.0 * n))) - 1.0);
}

static double cfar_fun(int k, int n, double t, double pfa) {
  double s = 0.0;
  for (int i = n; i > n - k; --i) s += log((double)i + t);
  return log_factorial_port(n) - log_factorial_port(n - k) - s - log(pfa);
}

static float compute_alpha() {
  double lo = 1.0, hi = 1e32;
  for (int it = 0; it < 300; ++it) {
    double mid = 0.5 * (lo + hi);
    if (cfar_fun(108, 144, mid, 1e-5) > 0.0)
      lo = mid;
    else
      hi = mid;
  }
  return (float)(0.5 * (lo + hi));
}

static const float g_alpha = compute_alpha();

extern "C" void kernel_launch(void* const* d_in, const int* in_sizes, int n_in,
                              void* d_out, int out_size, void* d_ws, size_t ws_size,
                              hipStream_t stream) {
  const float* in = (const float*)d_in[0];
  float* out = (float*)d_out;
  dim3 block(TX, 1);
  dim3 grid(RDIM / TX, VDIM / 2);
  hipLaunchKernelGGL(cfar_os_kernel, grid, block, 0, stream, in, out, g_alpha);
}

// Round 13
// 18.670 us; speedup vs baseline: 1.8211x; 1.0319x over previous
//
#include <hip/hip_runtime.h>
#include <cmath>

#ifndef M_PI
#define M_PI 3.14159265358979323846
#endif

typedef _Float16 h2 __attribute__((ext_vector_type(2)));

namespace {

constexpr int VDIM = 512;
constexpr int RDIM = 1024;
constexpr int TX = 256;          // pixel columns per block
constexpr int COLS = TX + 12;    // 268 cols incl. halo
constexpr int NPAIR = COLS - 1;  // 267 adjacent-col pairs

constexpr int SP_W = 28;  // h2 per pair row (112 B, 16B-aligned)

struct Net {
  int cnt;
  int a[96];
  int b[96];
};

// Batcher odd-even mergesort (arbitrary n), descending (max to low index).
constexpr Net make_batcher(int n) {
  Net net{};
  net.cnt = 0;
  for (int p = 1; p < n; p *= 2)
    for (int k = p; k >= 1; k /= 2)
      for (int j = k % p; j + k < n; j += 2 * k)
        for (int i = 0; i < k && i + j + k < n; ++i)
          if ((i + j) / (2 * p) == (i + j + k) / (2 * p)) {
            net.a[net.cnt] = i + j;
            net.b[net.cnt] = i + j + k;
            ++net.cnt;
          }
  return net;
}

// Descending sorter for a BITONIC input of length n (front +inf pads elided).
constexpr Net make_bitonic_desc(int n) {
  int P = 1;
  while (P < n) P *= 2;
  int F = P - n;
  Net net{};
  net.cnt = 0;
  for (int d = P / 2; d >= 1; d /= 2)
    for (int i = F; i + d < P; ++i)
      if ((i & d) == 0) {
        net.a[net.cnt] = i - F;
        net.b[net.cnt] = i - F + d;
        ++net.cnt;
      }
  return net;
}

constexpr Net NET8 = make_batcher(8);
constexpr Net NET5 = make_batcher(5);
constexpr Net B13 = make_bitonic_desc(13);
constexpr Net B16 = make_bitonic_desc(16);
constexpr Net B26 = make_bitonic_desc(26);
constexpr Net B32 = make_bitonic_desc(32);
constexpr Net B36 = make_bitonic_desc(36);

}  // namespace

__device__ __forceinline__ h2 mk2(_Float16 a, _Float16 b) {
  h2 v;
  v.x = a;
  v.y = b;
  return v;
}
// Force single-instruction packed comparators (VOP3P). The entire kernel's
// comparator traffic flows through these two functions.
__device__ __forceinline__ h2 pmax(h2 a, h2 b) {
  h2 r;
  asm("v_pk_max_f16 %0, %1, %2" : "=v"(r) : "v"(a), "v"(b));
  return r;
}
__device__ __forceinline__ h2 pmin(h2 a, h2 b) {
  h2 r;
  asm("v_pk_min_f16 %0, %1, %2" : "=v"(r) : "v"(a), "v"(b));
  return r;
}
__device__ __forceinline__ h2 bch(float f) { return __builtin_bit_cast(h2, f); }
__device__ __forceinline__ float bcf(h2 h) { return __builtin_bit_cast(float, h); }

#define DEF_NET(NAME, NET, L)                                       \
  __device__ __forceinline__ void NAME(h2(&v)[L]) {                 \
    _Pragma("unroll") for (int c = 0; c < NET.cnt; ++c) {           \
      h2 a = v[NET.a[c]], b = v[NET.b[c]];                          \
      v[NET.a[c]] = pmax(a, b);                                     \
      v[NET.b[c]] = pmin(a, b);                                     \
    }                                                               \
  }

DEF_NET(net8p, NET8, 8)
DEF_NET(net5p, NET5, 5)
DEF_NET(b13p, B13, 13)
DEF_NET(b16p, B16, 16)
DEF_NET(b26p, B26, 26)
DEF_NET(b32p, B32, 32)
DEF_NET(b36p, B36, 36)

// one column, both rows packed: f = sorted-13 desc, g = sorted gap-8 desc
__device__ __forceinline__ void col_chain(const h2 (&c)[13], h2 (&f)[13], h2 (&g)[8]) {
  g[0] = c[0]; g[1] = c[1]; g[2] = c[2]; g[3] = c[3];
  g[4] = c[9]; g[5] = c[10]; g[6] = c[11]; g[7] = c[12];
  net8p(g);
  h2 m[5] = {c[4], c[5], c[6], c[7], c[8]};
  net5p(m);
#pragma unroll
  for (int p = 0; p < 8; ++p) f[p] = g[p];
  f[8] = m[4]; f[9] = m[3]; f[10] = m[2]; f[11] = m[1]; f[12] = m[0];
  b13p(f);
}

// flat pair rows (112B stride): 7x ds_read_b128 off one base + imm offsets
__device__ __forceinline__ void ld26(const h2* __restrict__ row, h2 (&d)[26]) {
#pragma unroll
  for (int k = 0; k < 6; ++k) {
    float4 w = *(const float4*)(row + 4 * k);
    d[4 * k + 0] = bch(w.x); d[4 * k + 1] = bch(w.y);
    d[4 * k + 2] = bch(w.z); d[4 * k + 3] = bch(w.w);
  }
  float2 w = *(const float2*)(row + 24);
  d[24] = bch(w.x); d[25] = bch(w.y);
}

__device__ __forceinline__ void ldg8(const h2* SGa, const h2* SGb, int c, h2 (&d)[8]) {
  float4 a = *(const float4*)(SGa + 4 * c);
  float4 b = *(const float4*)(SGb + 4 * c);
  d[0] = bch(a.x); d[1] = bch(a.y); d[2] = bch(a.z); d[3] = bch(a.w);
  d[4] = bch(b.x); d[5] = bch(b.y); d[6] = bch(b.z); d[7] = bch(b.w);
}

// top-36 multiset of two descending sorted-26 lists -> bitonic-36
__device__ __forceinline__ void cap36(h2 (&S)[36], const h2 (&x)[26], const h2 (&y)[26]) {
#pragma unroll
  for (int i = 0; i < 10; ++i) S[i] = x[i];
#pragma unroll
  for (int i = 10; i < 26; ++i) S[i] = pmax(x[i], y[35 - i]);
#pragma unroll
  for (int i = 26; i < 36; ++i) S[i] = y[35 - i];
}

__global__ __launch_bounds__(256, 4) void cfar_os_kernel(const float* __restrict__ in,
                                                         float* __restrict__ out,
                                                         float alpha) {
  __shared__ __attribute__((aligned(16))) h2 SP[NPAIR * SP_W];  // sorted-26 pairs, flat
  __shared__ __attribute__((aligned(16))) h2 SGa[COLS * 4];     // gap-8 lo half
  __shared__ __attribute__((aligned(16))) h2 SGb[COLS * 4];     // gap-8 hi half

  const int t = threadIdx.x;
  const int r0 = blockIdx.y * 2;  // row pair (r0 in .x, r0+1 in .y)
  const int c0 = blockIdx.x * TX;

  // ---- cooperative stage: col-pair task, 2 cols x 2 rows per task ----
  for (int cc = t; cc < NPAIR; cc += 256) {
    const int gl = (c0 + cc - 6) & (RDIM - 1);
    const int gr = (gl + 1) & (RDIM - 1);
    float rwx[14], rwy[14];
#pragma unroll
    for (int dy = 0; dy < 14; ++dy) {
      const int rb = ((r0 + dy - 6) & (VDIM - 1)) << 10;
      rwx[dy] = in[rb + gl];
      rwy[dy] = in[rb + gr];
    }
    h2 cL[13], cR[13];
#pragma unroll
    for (int dy = 0; dy < 13; ++dy) {
      cL[dy] = mk2((_Float16)rwx[dy], (_Float16)rwx[dy + 1]);
      cR[dy] = mk2((_Float16)rwy[dy], (_Float16)rwy[dy + 1]);
    }
    h2 fL[13], gL[8], fR[13], gR[8];
    col_chain(cL, fL, gL);
    col_chain(cR, fR, gR);
    h2 v[26];
#pragma unroll
    for (int j = 0; j < 13; ++j) v[j] = fL[j];
#pragma unroll
    for (int j = 0; j < 13; ++j) v[13 + j] = fR[12 - j];
    b26p(v);  // sorted-26 desc, both rows

    h2* row = SP + cc * SP_W;
#pragma unroll
    for (int k = 0; k < 6; ++k)
      *(float4*)(row + 4 * k) = make_float4(bcf(v[4 * k]), bcf(v[4 * k + 1]),
                                            bcf(v[4 * k + 2]), bcf(v[4 * k + 3]));
    *(float2*)(row + 24) = make_float2(bcf(v[24]), bcf(v[25]));

    *(float4*)(SGa + 4 * cc) = make_float4(bcf(gL[0]), bcf(gL[1]), bcf(gL[2]), bcf(gL[3]));
    *(float4*)(SGb + 4 * cc) = make_float4(bcf(gL[4]), bcf(gL[5]), bcf(gL[6]), bcf(gL[7]));
  }
  __syncthreads();

  // ---- per-pixel-pair phase: gap branch first (minimal register liveness) ----
  h2 T[36];
  {
    h2 gc0[8], gc1[8], gc2[8], gc3[8], gc4[8];
    ldg8(SGa, SGb, t + 4, gc0);
    ldg8(SGa, SGb, t + 5, gc1);
    ldg8(SGa, SGb, t + 6, gc2);
    ldg8(SGa, SGb, t + 7, gc3);
    ldg8(SGa, SGb, t + 8, gc4);
    h2 g1[16], g2[16];
#pragma unroll
    for (int j = 0; j < 8; ++j) { g1[j] = gc0[j]; g1[8 + j] = gc1[7 - j]; }
    b16p(g1);
#pragma unroll
    for (int j = 0; j < 8; ++j) { g2[j] = gc2[j]; g2[8 + j] = gc3[7 - j]; }
    b16p(g2);
    h2 Gm[32];
#pragma unroll
    for (int j = 0; j < 16; ++j) { Gm[j] = g1[j]; Gm[16 + j] = g2[15 - j]; }
    b32p(Gm);
    // cap 40 -> bitonic 36: [Gm desc (32) | gc4 asc tail]
#pragma unroll
    for (int j = 0; j < 28; ++j) T[j] = Gm[j];
#pragma unroll
    for (int j = 28; j < 32; ++j) T[j] = pmax(Gm[j], gc4[35 - j]);
#pragma unroll
    for (int j = 32; j < 36; ++j) T[j] = gc4[35 - j];
    b36p(T);  // sorted top-36 of the 40 gap cells
  }

  // ---- B-side pairs, fold chain on single accumulator S ----
  h2 S[36];
  {
    h2 x[26], y[26];
    ld26(SP + (t + 9) * SP_W, x);
    ld26(SP + (t + 11) * SP_W, y);
    cap36(S, x, y);
  }
  b36p(S);  // #1

#pragma unroll
  for (int i = 0; i < 36; ++i) S[i] = pmax(S[i], T[35 - i]);  // fold gap top-36
  h2 x1[26];
  ld26(SP + (t + 0) * SP_W, x1);  // A-pair 1 (dx -6,-5)
  b36p(S);  // #2

#pragma unroll
  for (int i = 10; i < 36; ++i) S[i] = pmax(S[i], x1[35 - i]);
  h2 q[26];
  ld26(SP + (t + 2) * SP_W, q);  // A-pair 2 (dx -4,-3)
  b36p(S);  // #3

  // final rank identity, tree-min:
  // ans = min(S_9, min_{i=10..35} max(S_i, q_{35-i}))
  h2 mm[27];
#pragma unroll
  for (int i = 0; i < 26; ++i) mm[i] = pmax(S[10 + i], q[25 - i]);
  mm[26] = S[9];
#pragma unroll
  for (int i = 0; i < 13; ++i) mm[i] = pmin(mm[i], mm[i + 13]);
  mm[13] = mm[26];
#pragma unroll
  for (int i = 0; i < 7; ++i) mm[i] = pmin(mm[i], mm[i + 7]);
#pragma unroll
  for (int i = 0; i < 3; ++i) mm[i] = pmin(mm[i], mm[i + 3]);
  mm[0] = pmin(pmin(mm[0], mm[1]), pmin(mm[2], mm[6]));

  const int oc = c0 + t;
  out[(r0 << 10) + oc] = alpha * (float)mm[0].x;
  out[((r0 + 1) << 10) + oc] = alpha * (float)mm[0].y;
}

// ---- host-side faithful port of the reference ALPHA computation ----
static double log_factorial_port(int n_) {
  double n = n_ + 1.0;
  if (n < 9.0) {
    double f = 1.0;
    for (int i = 2; i <= (int)(n + 0.5); ++i) f *= (double)i;
    return log(f);
  }
  return 0.5 * (log(2.0 * M_PI) - log(n)) +
         n * (log(n + 1.0 / (12.0 * n - 1.0 / (10.0 * n))) - 1.0);
}

static double cfar_fun(int k, int n, double t, double pfa) {
  double s = 0.0;
  for (int i = n; i > n - k; --i) s += log((double)i + t);
  return log_factorial_port(n) - log_factorial_port(n - k) - s - log(pfa);
}

static float compute_alpha() {
  double lo = 1.0, hi = 1e32;
  for (int it = 0; it < 300; ++it) {
    double mid = 0.5 * (lo + hi);
    if (cfar_fun(108, 144, mid, 1e-5) > 0.0)
      lo = mid;
    else
      hi = mid;
  }
  return (float)(0.5 * (lo + hi));
}

static const float g_alpha = compute_alpha();

extern "C" void kernel_launch(void* const* d_in, const int* in_sizes, int n_in,
                              void* d_out, int out_size, void* d_ws, size_t ws_size,
                              hipStream_t stream) {
  const float* in = (const float*)d_in[0];
  float* out = (float*)d_out;
  dim3 block(TX, 1);
  dim3 grid(RDIM / TX, VDIM / 2);
  hipLaunchKernelGGL(cfar_os_kernel, grid, block, 0, stream, in, out, g_alpha);
}

// Round 14
// 17.305 us; speedup vs baseline: 1.9647x; 1.0789x over previous
//
#include <hip/hip_runtime.h>
#include <cmath>

#ifndef M_PI
#define M_PI 3.14159265358979323846
#endif

typedef _Float16 h2 __attribute__((ext_vector_type(2)));

namespace {

constexpr int VDIM = 512;
constexpr int RDIM = 1024;
constexpr int TX = 256;          // pixel columns per block
constexpr int COLS = TX + 12;    // 268 cols incl. halo
constexpr int NPAIR = COLS - 1;  // 267 adjacent-col pairs

constexpr int SP_W = 28;  // h2 per pair row (112 B, 16B-aligned)

struct Net {
  int cnt;
  int a[96];
  int b[96];
};

// Batcher odd-even mergesort (arbitrary n), descending (max to low index).
constexpr Net make_batcher(int n) {
  Net net{};
  net.cnt = 0;
  for (int p = 1; p < n; p *= 2)
    for (int k = p; k >= 1; k /= 2)
      for (int j = k % p; j + k < n; j += 2 * k)
        for (int i = 0; i < k && i + j + k < n; ++i)
          if ((i + j) / (2 * p) == (i + j + k) / (2 * p)) {
            net.a[net.cnt] = i + j;
            net.b[net.cnt] = i + j + k;
            ++net.cnt;
          }
  return net;
}

// Descending sorter for a BITONIC input of length n (front +inf pads elided).
constexpr Net make_bitonic_desc(int n) {
  int P = 1;
  while (P < n) P *= 2;
  int F = P - n;
  Net net{};
  net.cnt = 0;
  for (int d = P / 2; d >= 1; d /= 2)
    for (int i = F; i + d < P; ++i)
      if ((i & d) == 0) {
        net.a[net.cnt] = i - F;
        net.b[net.cnt] = i - F + d;
        ++net.cnt;
      }
  return net;
}

constexpr Net NET8 = make_batcher(8);
constexpr Net NET5 = make_batcher(5);
constexpr Net B13 = make_bitonic_desc(13);
constexpr Net B16 = make_bitonic_desc(16);
constexpr Net B26 = make_bitonic_desc(26);
constexpr Net B32 = make_bitonic_desc(32);
constexpr Net B36 = make_bitonic_desc(36);

}  // namespace

__device__ __forceinline__ h2 mk2(_Float16 a, _Float16 b) {
  h2 v;
  v.x = a;
  v.y = b;
  return v;
}
// Single-instruction packed comparators (VOP3P). All comparator traffic
// flows through these two functions.
__device__ __forceinline__ h2 pmax(h2 a, h2 b) {
  h2 r;
  asm("v_pk_max_f16 %0, %1, %2" : "=v"(r) : "v"(a), "v"(b));
  return r;
}
__device__ __forceinline__ h2 pmin(h2 a, h2 b) {
  h2 r;
  asm("v_pk_min_f16 %0, %1, %2" : "=v"(r) : "v"(a), "v"(b));
  return r;
}
__device__ __forceinline__ h2 bch(float f) { return __builtin_bit_cast(h2, f); }
__device__ __forceinline__ float bcf(h2 h) { return __builtin_bit_cast(float, h); }

#define DEF_NET(NAME, NET, L)                                       \
  __device__ __forceinline__ void NAME(h2(&v)[L]) {                 \
    _Pragma("unroll") for (int c = 0; c < NET.cnt; ++c) {           \
      h2 a = v[NET.a[c]], b = v[NET.b[c]];                          \
      v[NET.a[c]] = pmax(a, b);                                     \
      v[NET.b[c]] = pmin(a, b);                                     \
    }                                                               \
  }

DEF_NET(net8p, NET8, 8)
DEF_NET(net5p, NET5, 5)
DEF_NET(b13p, B13, 13)
DEF_NET(b16p, B16, 16)
DEF_NET(b26p, B26, 26)
DEF_NET(b32p, B32, 32)
DEF_NET(b36p, B36, 36)

// one column, both rows packed: f = sorted-13 desc, g = sorted gap-8 desc
__device__ __forceinline__ void col_chain(const h2 (&c)[13], h2 (&f)[13], h2 (&g)[8]) {
  g[0] = c[0]; g[1] = c[1]; g[2] = c[2]; g[3] = c[3];
  g[4] = c[9]; g[5] = c[10]; g[6] = c[11]; g[7] = c[12];
  net8p(g);
  h2 m[5] = {c[4], c[5], c[6], c[7], c[8]};
  net5p(m);
#pragma unroll
  for (int p = 0; p < 8; ++p) f[p] = g[p];
  f[8] = m[4]; f[9] = m[3]; f[10] = m[2]; f[11] = m[1]; f[12] = m[0];
  b13p(f);
}

// P1: one column -> sorted-13 (first 13 h2 of SP row cc) + gap-8 (SGa/SGb)
__device__ __forceinline__ void col_task(const float* __restrict__ in, int r0, int c0,
                                         int cc, h2* __restrict__ SP,
                                         h2* __restrict__ SGa, h2* __restrict__ SGb) {
  const int gc = (c0 + cc - 6) & (RDIM - 1);
  float w[14];
#pragma unroll
  for (int dy = 0; dy < 14; ++dy)
    w[dy] = in[(((r0 + dy - 6) & (VDIM - 1)) << 10) + gc];
  h2 c[13];
#pragma unroll
  for (int dy = 0; dy < 13; ++dy) c[dy] = mk2((_Float16)w[dy], (_Float16)w[dy + 1]);
  h2 f[13], g[8];
  col_chain(c, f, g);
  h2* row = SP + cc * SP_W;
  *(float4*)(row + 0) = make_float4(bcf(f[0]), bcf(f[1]), bcf(f[2]), bcf(f[3]));
  *(float4*)(row + 4) = make_float4(bcf(f[4]), bcf(f[5]), bcf(f[6]), bcf(f[7]));
  *(float4*)(row + 8) = make_float4(bcf(f[8]), bcf(f[9]), bcf(f[10]), bcf(f[11]));
  *(float*)(row + 12) = bcf(f[12]);
  *(float4*)(SGa + 4 * cc) = make_float4(bcf(g[0]), bcf(g[1]), bcf(g[2]), bcf(g[3]));
  *(float4*)(SGb + 4 * cc) = make_float4(bcf(g[4]), bcf(g[5]), bcf(g[6]), bcf(g[7]));
}

// P2 read: rows cc and cc+1 sorted-13s -> bitonic-26 [L desc | R asc]
__device__ __forceinline__ void ld13x2(const h2* __restrict__ SP, int cc, h2 (&v)[26]) {
  const h2* L = SP + cc * SP_W;
  const h2* R = L + SP_W;
  float4 a0 = *(const float4*)(L + 0);
  float4 a1 = *(const float4*)(L + 4);
  float4 a2 = *(const float4*)(L + 8);
  float a3 = *(const float*)(L + 12);
  float4 b0 = *(const float4*)(R + 0);
  float4 b1 = *(const float4*)(R + 4);
  float4 b2 = *(const float4*)(R + 8);
  float b3 = *(const float*)(R + 12);
  v[0] = bch(a0.x); v[1] = bch(a0.y); v[2] = bch(a0.z); v[3] = bch(a0.w);
  v[4] = bch(a1.x); v[5] = bch(a1.y); v[6] = bch(a1.z); v[7] = bch(a1.w);
  v[8] = bch(a2.x); v[9] = bch(a2.y); v[10] = bch(a2.z); v[11] = bch(a2.w);
  v[12] = bch(a3);
  v[13] = bch(b3);
  v[14] = bch(b2.w); v[15] = bch(b2.z); v[16] = bch(b2.y); v[17] = bch(b2.x);
  v[18] = bch(b1.w); v[19] = bch(b1.z); v[20] = bch(b1.y); v[21] = bch(b1.x);
  v[22] = bch(b0.w); v[23] = bch(b0.z); v[24] = bch(b0.y); v[25] = bch(b0.x);
}

__device__ __forceinline__ void st26(h2* __restrict__ SP, int cc, const h2 (&v)[26]) {
  h2* row = SP + cc * SP_W;
#pragma unroll
  for (int k = 0; k < 6; ++k)
    *(float4*)(row + 4 * k) = make_float4(bcf(v[4 * k]), bcf(v[4 * k + 1]),
                                          bcf(v[4 * k + 2]), bcf(v[4 * k + 3]));
  *(float2*)(row + 24) = make_float2(bcf(v[24]), bcf(v[25]));
}

// flat pair rows (112B stride): 7x ds_read off one base + imm offsets
__device__ __forceinline__ void ld26(const h2* __restrict__ row, h2 (&d)[26]) {
#pragma unroll
  for (int k = 0; k < 6; ++k) {
    float4 w = *(const float4*)(row + 4 * k);
    d[4 * k + 0] = bch(w.x); d[4 * k + 1] = bch(w.y);
    d[4 * k + 2] = bch(w.z); d[4 * k + 3] = bch(w.w);
  }
  float2 w = *(const float2*)(row + 24);
  d[24] = bch(w.x); d[25] = bch(w.y);
}

__device__ __forceinline__ void ldg8(const h2* SGa, const h2* SGb, int c, h2 (&d)[8]) {
  float4 a = *(const float4*)(SGa + 4 * c);
  float4 b = *(const float4*)(SGb + 4 * c);
  d[0] = bch(a.x); d[1] = bch(a.y); d[2] = bch(a.z); d[3] = bch(a.w);
  d[4] = bch(b.x); d[5] = bch(b.y); d[6] = bch(b.z); d[7] = bch(b.w);
}

// top-36 multiset of two descending sorted-26 lists -> bitonic-36
__device__ __forceinline__ void cap36(h2 (&S)[36], const h2 (&x)[26], const h2 (&y)[26]) {
#pragma unroll
  for (int i = 0; i < 10; ++i) S[i] = x[i];
#pragma unroll
  for (int i = 10; i < 26; ++i) S[i] = pmax(x[i], y[35 - i]);
#pragma unroll
  for (int i = 26; i < 36; ++i) S[i] = y[35 - i];
}

__global__ __launch_bounds__(256, 4) void cfar_os_kernel(const float* __restrict__ in,
                                                         float* __restrict__ out,
                                                         float alpha) {
  __shared__ __attribute__((aligned(16))) h2 SP[COLS * SP_W];  // 268 rows
  __shared__ __attribute__((aligned(16))) h2 SGa[COLS * 4];    // gap-8 lo half
  __shared__ __attribute__((aligned(16))) h2 SGb[COLS * 4];    // gap-8 hi half

  const int t = threadIdx.x;
  const int r0 = blockIdx.y * 2;  // row pair (r0 in .x, r0+1 in .y)
  const int c0 = blockIdx.x * TX;

  // ---- P1: per-column sorted-13 + gap-8 (268 col tasks) ----
  col_task(in, r0, c0, t, SP, SGa, SGb);
  if (t < COLS - 256) col_task(in, r0, c0, 256 + t, SP, SGa, SGb);
  __syncthreads();

  // ---- P2: merge adjacent sorted-13s -> sorted-26 pairs (267 tasks) ----
  h2 v0[26], v1[26];
  ld13x2(SP, t, v0);
  const bool tail = (t < NPAIR - 256);
  if (tail) ld13x2(SP, 256 + t, v1);
  b26p(v0);
  if (tail) b26p(v1);
  __syncthreads();  // all sorted-13 reads complete before overwriting rows
  st26(SP, t, v0);
  if (tail) st26(SP, 256 + t, v1);
  __syncthreads();

  // ---- per-pixel-pair phase (identical to R13) ----
  h2 T[36];
  {
    h2 gc0[8], gc1[8], gc2[8], gc3[8], gc4[8];
    ldg8(SGa, SGb, t + 4, gc0);
    ldg8(SGa, SGb, t + 5, gc1);
    ldg8(SGa, SGb, t + 6, gc2);
    ldg8(SGa, SGb, t + 7, gc3);
    ldg8(SGa, SGb, t + 8, gc4);
    h2 g1[16], g2[16];
#pragma unroll
    for (int j = 0; j < 8; ++j) { g1[j] = gc0[j]; g1[8 + j] = gc1[7 - j]; }
    b16p(g1);
#pragma unroll
    for (int j = 0; j < 8; ++j) { g2[j] = gc2[j]; g2[8 + j] = gc3[7 - j]; }
    b16p(g2);
    h2 Gm[32];
#pragma unroll
    for (int j = 0; j < 16; ++j) { Gm[j] = g1[j]; Gm[16 + j] = g2[15 - j]; }
    b32p(Gm);
    // cap 40 -> bitonic 36: [Gm desc (32) | gc4 asc tail]
#pragma unroll
    for (int j = 0; j < 28; ++j) T[j] = Gm[j];
#pragma unroll
    for (int j = 28; j < 32; ++j) T[j] = pmax(Gm[j], gc4[35 - j]);
#pragma unroll
    for (int j = 32; j < 36; ++j) T[j] = gc4[35 - j];
    b36p(T);  // sorted top-36 of the 40 gap cells
  }

  // ---- B-side pairs, fold chain on single accumulator S ----
  h2 S[36];
  {
    h2 x[26], y[26];
    ld26(SP + (t + 9) * SP_W, x);
    ld26(SP + (t + 11) * SP_W, y);
    cap36(S, x, y);
  }
  b36p(S);  // #1

#pragma unroll
  for (int i = 0; i < 36; ++i) S[i] = pmax(S[i], T[35 - i]);  // fold gap top-36
  h2 x1[26];
  ld26(SP + (t + 0) * SP_W, x1);  // A-pair 1 (dx -6,-5)
  b36p(S);  // #2

#pragma unroll
  for (int i = 10; i < 36; ++i) S[i] = pmax(S[i], x1[35 - i]);
  h2 q[26];
  ld26(SP + (t + 2) * SP_W, q);  // A-pair 2 (dx -4,-3)
  b36p(S);  // #3

  // final rank identity, tree-min:
  // ans = min(S_9, min_{i=10..35} max(S_i, q_{35-i}))
  h2 mm[27];
#pragma unroll
  for (int i = 0; i < 26; ++i) mm[i] = pmax(S[10 + i], q[25 - i]);
  mm[26] = S[9];
#pragma unroll
  for (int i = 0; i < 13; ++i) mm[i] = pmin(mm[i], mm[i + 13]);
  mm[13] = mm[26];
#pragma unroll
  for (int i = 0; i < 7; ++i) mm[i] = pmin(mm[i], mm[i + 7]);
#pragma unroll
  for (int i = 0; i < 3; ++i) mm[i] = pmin(mm[i], mm[i + 3]);
  mm[0] = pmin(pmin(mm[0], mm[1]), pmin(mm[2], mm[6]));

  const int oc = c0 + t;
  out[(r0 << 10) + oc] = alpha * (float)mm[0].x;
  out[((r0 + 1) << 10) + oc] = alpha * (float)mm[0].y;
}

// ---- host-side faithful port of the reference ALPHA computation ----
static double log_factorial_port(int n_) {
  double n = n_ + 1.0;
  if (n < 9.0) {
    double f = 1.0;
    for (int i = 2; i <= (int)(n + 0.5); ++i) f *= (double)i;
    return log(f);
  }
  return 0.5 * (log(2.0 * M_PI) - log(n)) +
         n * (log(n + 1.0 / (12.0 * n - 1.0 / (10.0 * n))) - 1.0);
}

static double cfar_fun(int k, int n, double t, double pfa) {
  double s = 0.0;
  for (int i = n; i > n - k; --i) s += log((double)i + t);
  return log_factorial_port(n) - log_factorial_port(n - k) - s - log(pfa);
}

static float compute_alpha() {
  double lo = 1.0, hi = 1e32;
  for (int it = 0; it < 300; ++it) {
    double mid = 0.5 * (lo + hi);
    if (cfar_fun(108, 144, mid, 1e-5) > 0.0)
      lo = mid;
    else
      hi = mid;
  }
  return (float)(0.5 * (lo + hi));
}

static const float g_alpha = compute_alpha();

extern "C" void kernel_launch(void* const* d_in, const int* in_sizes, int n_in,
                              void* d_out, int out_size, void* d_ws, size_t ws_size,
                              hipStream_t stream) {
  const float* in = (const float*)d_in[0];
  float* out = (float*)d_out;
  dim3 block(TX, 1);
  dim3 grid(RDIM / TX, VDIM / 2);
  hipLaunchKernelGGL(cfar_os_kernel, grid, block, 0, stream, in, out, g_alpha);
}